// Round 17
// baseline (151.770 us; speedup 1.0000x reference)
//
#include <hip/hip_runtime.h>
#include <hip/hip_fp16.h>

#define TWO_PI_F 6.283185307179586f

__device__ __forceinline__ float clamp02pi(float x) {
    return fminf(fmaxf(x, 0.0f), TWO_PI_F);
}

__device__ __forceinline__ float2 cmul(const float2 a, const float2 b) {
    return make_float2(a.x * b.x - a.y * b.y, a.x * b.y + a.y * b.x);
}
__device__ __forceinline__ float2 cadd(const float2 a, const float2 b) {
    return make_float2(a.x + b.x, a.y + b.y);
}
__device__ __forceinline__ float2 cscale(const float s, const float2 a) {
    return make_float2(s * a.x, s * a.y);
}
__device__ __forceinline__ float2 imul(const float r, const float2 e) {  // i*r*e
    return make_float2(-r * e.y, r * e.x);
}
__device__ __forceinline__ float2 cfma(const float2 acc, const float2 a, const float2 b) {
    return make_float2(acc.x + a.x * b.x - a.y * b.y,
                       acc.y + a.x * b.y + a.y * b.x);
}

// half2 <-> float2 via bit_cast (register-only, no memory reinterpret).
__device__ __forceinline__ float2 h2f(const unsigned u) {
    return __half22float2(__builtin_bit_cast(__half2, u));
}
__device__ __forceinline__ unsigned f2h(const float2 f) {
    return __builtin_bit_cast(unsigned, __float22half2_rn(f));
}

// Band-4 composition of row r for one 4-layer step (math verbatim R12-R16 —
// verified, absmax 3.7e-9 fp32 / 7.45e-9 fp16).
__device__ __forceinline__ void compose_row(
    const float4 (*sE)[256], const float4 (*sO)[256], const int r,
    float4& h0, float4& h1)
{
    float2 f0, f1, f2, f3;
    if (r == 0) {
        const float4 q1 = sE[1][0], q0 = sE[0][0];
        const float2 e1 = make_float2(q1.x, q1.y);
        const float2 e0 = make_float2(q0.x, q0.y);
        const float2 v2 = cscale(q1.z, e1);
        const float2 v3 = make_float2(0.0f, q1.w);
        f2 = cadd(cmul(v2, cscale(q0.z, e0)), cmul(v3, imul(q0.w, e0)));
        f3 = cadd(cmul(v2, make_float2(0.0f, q0.w)), cscale(q0.z, v3));
        f0 = make_float2(0.0f, 0.0f);
        f1 = make_float2(0.0f, 0.0f);
    } else {
        const int pidx = (r - 1) >> 1;
        const int qidx = min(pidx + 1, 255);      // r=511: u2==0, value unused
        const float4 qO1 = sO[1][pidx], qO0 = sO[0][pidx];
        const float2 eO1 = make_float2(qO1.x, qO1.y);
        const float2 eO0 = make_float2(qO0.x, qO0.y);
        float2 w1, w2;
        if (r & 1) { w1 = cscale(qO1.z, eO1); w2 = make_float2(0.0f, qO1.w); }
        else       { w1 = imul(qO1.w, eO1);   w2 = make_float2(qO1.z, 0.0f); }
        const float2 u1 = cadd(cmul(w1, cscale(qO0.z, eO0)),
                               cmul(w2, imul(qO0.w, eO0)));
        const float2 u2 = cadd(cmul(w1, make_float2(0.0f, qO0.w)),
                               cscale(qO0.z, w2));
        const float4 qE1p = sE[1][pidx], qE1q = sE[1][qidx];
        const float4 qE0p = sE[0][pidx], qE0q = sE[0][qidx];
        const float2 eE1p = make_float2(qE1p.x, qE1p.y);
        const float2 eE1q = make_float2(qE1q.x, qE1q.y);
        const float2 eE0p = make_float2(qE0p.x, qE0p.y);
        const float2 eE0q = make_float2(qE0q.x, qE0q.y);
        const float2 v0 = cmul(u1, imul(qE1p.w, eE1p));
        const float2 v1 = cscale(qE1p.z, u1);
        const float2 v2 = cmul(u2, cscale(qE1q.z, eE1q));
        const float2 v3 = cmul(u2, make_float2(0.0f, qE1q.w));
        f0 = cadd(cmul(v0, cscale(qE0p.z, eE0p)), cmul(v1, imul(qE0p.w, eE0p)));
        f1 = cadd(cmul(v0, make_float2(0.0f, qE0p.w)), cscale(qE0p.z, v1));
        f2 = cadd(cmul(v2, cscale(qE0q.z, eE0q)), cmul(v3, imul(qE0q.w, eE0q)));
        f3 = cadd(cmul(v2, make_float2(0.0f, qE0q.w)), cscale(qE0q.z, v3));
    }
    h0 = make_float4(f0.x, f0.y, f1.x, f1.y);
    h1 = make_float4(f2.x, f2.y, f3.x, f3.y);
}

// ---------------------------------------------------------------------------
// Kernel 1 (verbatim R16 — verified): fused 2-level composition -> FP16
// band-8 operator. Mch8[j*1024 + (r&1)*512 + (r>>1)] and +256 hold row r's
// 8 complex coefs. Row 2t window base 2t-4; row 2t+1 base 2t-2; out-of-window
// entries EXACT zeros.
// ---------------------------------------------------------------------------
__global__ __launch_bounds__(512) void compose8_kernel(
    const float* __restrict__ pe, const float* __restrict__ po,
    const float* __restrict__ le, const float* __restrict__ ie,
    const float* __restrict__ lo, const float* __restrict__ io,
    uint4* __restrict__ Mch8)
{
    const int j = blockIdx.x;    // superstep8 0..127
    const int t = threadIdx.x;   // 0..511

    __shared__ float4 sE[4][256];
    __shared__ float4 sO[4][256];
    __shared__ float4 B4[2][512][2];

#pragma unroll
    for (int q = 0; q < 2; ++q) {
        const int item = q * 512 + t;
        const int sub = item >> 8;
        const int pp  = item & 255;
        {
            const int idx = (4 * j + sub) * 256 + pp;
            float s, c;
            __sincosf(clamp02pi(pe[idx]), &s, &c);
            const float a = sqrtf(1.0f - le[idx]);
            sE[sub][pp] = make_float4(c, s, a * sqrtf(0.5f + ie[idx]),
                                            a * sqrtf(0.5f - ie[idx]));
        }
        {
            float4 qv = make_float4(1.0f, 0.0f, 1.0f, 0.0f);
            if (pp < 255) {
                const int odx = (4 * j + sub) * 255 + pp;
                float s, c;
                __sincosf(clamp02pi(po[odx]), &s, &c);
                const float a = sqrtf(1.0f - lo[odx]);
                qv = make_float4(c, s, a * sqrtf(0.5f + io[odx]),
                                       a * sqrtf(0.5f - io[odx]));
            }
            sO[sub][pp] = qv;
        }
    }
    __syncthreads();

#pragma unroll
    for (int s = 0; s < 2; ++s) {
        float4 h0, h1;
        compose_row(&sE[2 * s], &sO[2 * s], t, h0, h1);
        B4[s][t][0] = h0;
        B4[s][t][1] = h1;
    }
    __syncthreads();

    const int r = t;
    const int base = (r & 1) ? (r - 1) : (r - 2);
    const float4 wv0 = B4[1][r][0], wv1 = B4[1][r][1];
    const float2 w0 = make_float2(wv0.x, wv0.y), w1 = make_float2(wv0.z, wv0.w);
    const float2 w2 = make_float2(wv1.x, wv1.y), w3 = make_float2(wv1.z, wv1.w);
    float2 p0 = make_float2(0.f,0.f), p1 = p0, p2 = p0, p3 = p0,
           p4 = p0, p5 = p0, p6 = p0, p7 = p0;
    {   const int k = min(max(base, 0), 511);
        const float4 a = B4[0][k][0], b = B4[0][k][1];
        p0 = cfma(p0, w0, make_float2(a.x, a.y));
        p1 = cfma(p1, w0, make_float2(a.z, a.w));
        p2 = cfma(p2, w0, make_float2(b.x, b.y));
        p3 = cfma(p3, w0, make_float2(b.z, b.w)); }
    {   const int k = min(max(base + 1, 0), 511);
        const float4 a = B4[0][k][0], b = B4[0][k][1];
        p2 = cfma(p2, w1, make_float2(a.x, a.y));
        p3 = cfma(p3, w1, make_float2(a.z, a.w));
        p4 = cfma(p4, w1, make_float2(b.x, b.y));
        p5 = cfma(p5, w1, make_float2(b.z, b.w)); }
    {   const int k = min(max(base + 2, 0), 511);
        const float4 a = B4[0][k][0], b = B4[0][k][1];
        p2 = cfma(p2, w2, make_float2(a.x, a.y));
        p3 = cfma(p3, w2, make_float2(a.z, a.w));
        p4 = cfma(p4, w2, make_float2(b.x, b.y));
        p5 = cfma(p5, w2, make_float2(b.z, b.w)); }
    {   const int k = min(max(base + 3, 0), 511);
        const float4 a = B4[0][k][0], b = B4[0][k][1];
        p4 = cfma(p4, w3, make_float2(a.x, a.y));
        p5 = cfma(p5, w3, make_float2(a.z, a.w));
        p6 = cfma(p6, w3, make_float2(b.x, b.y));
        p7 = cfma(p7, w3, make_float2(b.z, b.w)); }
    uint4* dst = Mch8 + (size_t)j * 1024 + (r & 1) * 512 + (r >> 1);
    dst[0]   = make_uint4(f2h(p0), f2h(p1), f2h(p2), f2h(p3));
    dst[256] = make_uint4(f2h(p4), f2h(p5), f2h(p6), f2h(p7));
}

// ---------------------------------------------------------------------------
// Kernel 2: band-16 composition from two band-8s (fp32 accumulate).
// Block j (0..63): S1 = superstep8 2j, S2 = superstep8 2j+1; thread = row r.
// P[r, base16+off_m+n] += w_m * S1[k=b2+m, n],  off_m = m+(m&1) (derived for
// both parities), b2 = r-4+(r&1), base16 = r-8+(r&1). k clamped; OOB w_m are
// EXACT zeros (inherited from band-8's verified zero structure) -> result
// out-of-window entries are exact zeros, so the mesh pad trick stays valid
// (incl. odd rows' 15-wide band: entry 15 provably 0 via S1's zero tail).
// Output: Mc16[j*2048 + h*256 + (r>>1)], h = (r&1)*4 + 0..3 (4 uint4/row).
// ---------------------------------------------------------------------------
#define ACC8(W, K, PA, PB, PC, PD, PE, PF, PG, PH) { \
    const int k_ = min(max((K), 0), 511); \
    const int ia_ = s1base + (k_ & 1) * 512 + (k_ >> 1); \
    const uint4 ra_ = Mch8[ia_]; \
    const uint4 rb_ = Mch8[ia_ + 256]; \
    PA = cfma(PA, W, h2f(ra_.x)); PB = cfma(PB, W, h2f(ra_.y)); \
    PC = cfma(PC, W, h2f(ra_.z)); PD = cfma(PD, W, h2f(ra_.w)); \
    PE = cfma(PE, W, h2f(rb_.x)); PF = cfma(PF, W, h2f(rb_.y)); \
    PG = cfma(PG, W, h2f(rb_.z)); PH = cfma(PH, W, h2f(rb_.w)); \
}

__global__ __launch_bounds__(512) void compose16_kernel(
    const uint4* __restrict__ Mch8, uint4* __restrict__ Mc16)
{
    const int j = blockIdx.x;    // superstep16 0..63
    const int r = threadIdx.x;   // row 0..511

    const int i2 = (2 * j + 1) * 1024 + (r & 1) * 512 + (r >> 1);
    const uint4 wa = Mch8[i2];
    const uint4 wb = Mch8[i2 + 256];
    const float2 w0 = h2f(wa.x), w1 = h2f(wa.y), w2 = h2f(wa.z), w3 = h2f(wa.w);
    const float2 w4 = h2f(wb.x), w5 = h2f(wb.y), w6 = h2f(wb.z), w7 = h2f(wb.w);

    const int b2 = r - 4 + (r & 1);
    const int s1base = (2 * j) * 1024;

    float2 p0  = make_float2(0.f,0.f), p1 = p0,  p2 = p0,  p3 = p0,
           p4  = p0, p5  = p0, p6  = p0, p7  = p0,
           p8  = p0, p9  = p0, p10 = p0, p11 = p0,
           p12 = p0, p13 = p0, p14 = p0, p15 = p0;

    ACC8(w0, b2 + 0, p0, p1, p2,  p3,  p4,  p5,  p6,  p7);   // off 0
    ACC8(w1, b2 + 1, p2, p3, p4,  p5,  p6,  p7,  p8,  p9);   // off 2
    ACC8(w2, b2 + 2, p2, p3, p4,  p5,  p6,  p7,  p8,  p9);   // off 2
    ACC8(w3, b2 + 3, p4, p5, p6,  p7,  p8,  p9,  p10, p11);  // off 4
    ACC8(w4, b2 + 4, p4, p5, p6,  p7,  p8,  p9,  p10, p11);  // off 4
    ACC8(w5, b2 + 5, p6, p7, p8,  p9,  p10, p11, p12, p13);  // off 6
    ACC8(w6, b2 + 6, p6, p7, p8,  p9,  p10, p11, p12, p13);  // off 6
    ACC8(w7, b2 + 7, p8, p9, p10, p11, p12, p13, p14, p15);  // off 8

    uint4* dst = Mc16 + (size_t)j * 2048 + (r & 1) * 1024 + (r >> 1);
    dst[0]   = make_uint4(f2h(p0),  f2h(p1),  f2h(p2),  f2h(p3));
    dst[256] = make_uint4(f2h(p4),  f2h(p5),  f2h(p6),  f2h(p7));
    dst[512] = make_uint4(f2h(p8),  f2h(p9),  f2h(p10), f2h(p11));
    dst[768] = make_uint4(f2h(p12), f2h(p13), f2h(p14), f2h(p15));
}

// fp16 band partial apply: q packs 4 complex coefs over inputs (a,b,d,e).
__device__ __forceinline__ float2 hrow4(const uint4 q, const float2 a,
                                        const float2 b, const float2 d,
                                        const float2 e, float2 acc)
{
    acc = cfma(acc, h2f(q.x), a);
    acc = cfma(acc, h2f(q.y), b);
    acc = cfma(acc, h2f(q.z), d);
    acc = cfma(acc, h2f(q.w), e);
    return acc;
}

// ---------------------------------------------------------------------------
// Kernel 3: band-16 pair-thread scan. Structure = R15/R16's proven shape
// (grid 512 x 256, 2 blocks/CU), but 64 supersteps of 16 layers — barriers
// halved again (64 total). Thread t owns rows (2t,2t+1); state in padded
// double-buffered fp32 LDS (pads 0..3 / 260..263 zero, multiplied by exactly-
// zero band coefs). Per superstep: 8 uint4 coef loads (prefetched, named
// regs), 8 x ds_read_b128 (stride 16 B = 2-way = free), 32 cfma, 1 write,
// ONE barrier. Row 2t window pairs t-4..t+3; row 2t+1 pairs t-3..t+4.
// ---------------------------------------------------------------------------
__global__ __launch_bounds__(256) void mesh16_kernel(
    const uint4* __restrict__ Mc16,
    const float* __restrict__ pout,
    float* __restrict__ out, const int out_size)
{
    const int t   = threadIdx.x;   // row-pair 0..255
    const int col = blockIdx.x;    // column 0..511

    __shared__ float4 S[2][264];   // [buf][pair+4] = {T.x,T.y,B.x,B.y}

    float2 T = make_float2((2 * t     == col) ? 1.0f : 0.0f, 0.0f);
    float2 B = make_float2((2 * t + 1 == col) ? 1.0f : 0.0f, 0.0f);
    S[0][t + 4] = make_float4(T.x, T.y, B.x, B.y);
    if (t < 4) {
        const float4 z = make_float4(0.f, 0.f, 0.f, 0.f);
        S[0][t] = z; S[1][t] = z;
        S[0][260 + t] = z; S[1][260 + t] = z;
    }

    uint4 c0 = Mc16[t],        c1 = Mc16[256 + t],
          c2 = Mc16[512 + t],  c3 = Mc16[768 + t],
          c4 = Mc16[1024 + t], c5 = Mc16[1280 + t],
          c6 = Mc16[1536 + t], c7 = Mc16[1792 + t];
    __syncthreads();

#pragma unroll 1
    for (int i = 0; i < 64; ++i) {
        const int nb = ((i + 1) & 63) * 2048 + t;       // prefetch (wrap ok)
        const uint4 n0 = Mc16[nb],        n1 = Mc16[nb + 256],
                    n2 = Mc16[nb + 512],  n3 = Mc16[nb + 768],
                    n4 = Mc16[nb + 1024], n5 = Mc16[nb + 1280],
                    n6 = Mc16[nb + 1536], n7 = Mc16[nb + 1792];

        const float4* SS = S[i & 1];
        const float4 q0 = SS[t],     q1 = SS[t + 1], q2 = SS[t + 2],
                     q3 = SS[t + 3], q5 = SS[t + 5], q6 = SS[t + 6],
                     q7 = SS[t + 7], q8 = SS[t + 8];

        // row 2t: pairs t-4..t+3
        float2 YT = hrow4(c0, make_float2(q0.x, q0.y), make_float2(q0.z, q0.w),
                              make_float2(q1.x, q1.y), make_float2(q1.z, q1.w),
                          make_float2(0.f, 0.f));
        YT = hrow4(c1, make_float2(q2.x, q2.y), make_float2(q2.z, q2.w),
                       make_float2(q3.x, q3.y), make_float2(q3.z, q3.w), YT);
        YT = hrow4(c2, T, B,
                       make_float2(q5.x, q5.y), make_float2(q5.z, q5.w), YT);
        YT = hrow4(c3, make_float2(q6.x, q6.y), make_float2(q6.z, q6.w),
                       make_float2(q7.x, q7.y), make_float2(q7.z, q7.w), YT);
        // row 2t+1: pairs t-3..t+4 (16th band entry is exact 0)
        float2 YB = hrow4(c4, make_float2(q1.x, q1.y), make_float2(q1.z, q1.w),
                              make_float2(q2.x, q2.y), make_float2(q2.z, q2.w),
                          make_float2(0.f, 0.f));
        YB = hrow4(c5, make_float2(q3.x, q3.y), make_float2(q3.z, q3.w),
                       T, B, YB);
        YB = hrow4(c6, make_float2(q5.x, q5.y), make_float2(q5.z, q5.w),
                       make_float2(q6.x, q6.y), make_float2(q6.z, q6.w), YB);
        YB = hrow4(c7, make_float2(q7.x, q7.y), make_float2(q7.z, q7.w),
                       make_float2(q8.x, q8.y), make_float2(q8.z, q8.w), YB);

        T = YT; B = YB;
        S[(i + 1) & 1][t + 4] = make_float4(T.x, T.y, B.x, B.y);
        __syncthreads();

        c0 = n0; c1 = n1; c2 = n2; c3 = n3;
        c4 = n4; c5 = n5; c6 = n6; c7 = n7;
    }

    // ---- output phases; expected output = Re(M), row-major, guarded ----
    float s0p, c0p, s1p, c1p;
    __sincosf(clamp02pi(pout[2 * t]),     &s0p, &c0p);
    __sincosf(clamp02pi(pout[2 * t + 1]), &s1p, &c1p);
    const int i0 = (2 * t) * 512 + col;
    const int i1 = i0 + 512;
    if (i0 < out_size) out[i0] = c0p * T.x - s0p * T.y;
    if (i1 < out_size) out[i1] = c1p * B.x - s1p * B.y;
}

// ---------------------------------------------------------------------------
// Mid-fallback (verbatim R16 mesh, known-passing at 81 us) — used if ws fits
// band-8 but not band-16.
// ---------------------------------------------------------------------------
__global__ __launch_bounds__(256) void mesh8h_kernel(
    const uint4* __restrict__ Mch,
    const float* __restrict__ pout,
    float* __restrict__ out, const int out_size)
{
    const int t   = threadIdx.x;
    const int col = blockIdx.x;

    __shared__ float4 S[2][260];

    float2 T = make_float2((2 * t     == col) ? 1.0f : 0.0f, 0.0f);
    float2 B = make_float2((2 * t + 1 == col) ? 1.0f : 0.0f, 0.0f);
    S[0][t + 2] = make_float4(T.x, T.y, B.x, B.y);
    if (t < 2) {
        const float4 z = make_float4(0.f, 0.f, 0.f, 0.f);
        S[0][t] = z; S[1][t] = z;
        S[0][258 + t] = z; S[1][258 + t] = z;
    }

    uint4 c0 = Mch[t],       c1 = Mch[256 + t],
          c2 = Mch[512 + t], c3 = Mch[768 + t];
    __syncthreads();

#pragma unroll 1
    for (int i = 0; i < 128; ++i) {
        const int nb = ((i + 1) & 127) * 1024 + t;
        const uint4 n0 = Mch[nb],       n1 = Mch[nb + 256],
                    n2 = Mch[nb + 512], n3 = Mch[nb + 768];

        const float4* SS = S[i & 1];
        const float4 s0 = SS[t], s1 = SS[t + 1], s3 = SS[t + 3], s4 = SS[t + 4];

        float2 YT = hrow4(c0, make_float2(s0.x, s0.y), make_float2(s0.z, s0.w),
                              make_float2(s1.x, s1.y), make_float2(s1.z, s1.w),
                          make_float2(0.f, 0.f));
        YT = hrow4(c1, T, B,
                       make_float2(s3.x, s3.y), make_float2(s3.z, s3.w), YT);
        float2 YB = hrow4(c2, make_float2(s1.x, s1.y), make_float2(s1.z, s1.w),
                              T, B, make_float2(0.f, 0.f));
        YB = hrow4(c3, make_float2(s3.x, s3.y), make_float2(s3.z, s3.w),
                       make_float2(s4.x, s4.y), make_float2(s4.z, s4.w), YB);
        T = YT; B = YB;
        S[(i + 1) & 1][t + 2] = make_float4(T.x, T.y, B.x, B.y);
        __syncthreads();

        c0 = n0; c1 = n1; c2 = n2; c3 = n3;
    }

    float s0p, c0p, s1p, c1p;
    __sincosf(clamp02pi(pout[2 * t]),     &s0p, &c0p);
    __sincosf(clamp02pi(pout[2 * t + 1]), &s1p, &c1p);
    const int i0 = (2 * t) * 512 + col;
    const int i1 = i0 + 512;
    if (i0 < out_size) out[i0] = c0p * T.x - s0p * T.y;
    if (i1 < out_size) out[i1] = c1p * B.x - s1p * B.y;
}

extern "C" void kernel_launch(void* const* d_in, const int* in_sizes, int n_in,
                              void* d_out, int out_size, void* d_ws, size_t ws_size,
                              hipStream_t stream)
{
    const float* pe   = (const float*)d_in[0];  // pc_even_phases  [512][256]
    const float* po   = (const float*)d_in[1];  // pc_odd_phases   [512][255]
    const float* pout = (const float*)d_in[2];  // pc_out_phases   [512]
    const float* le   = (const float*)d_in[3];  // mmi_loss_even   [512][256]
    const float* ie   = (const float*)d_in[4];  // mmi_imb_even    [512][256]
    const float* lo   = (const float*)d_in[5];  // mmi_loss_odd    [512][255]
    const float* io   = (const float*)d_in[6];  // mmi_imb_odd     [512][255]

    const size_t need8  = (size_t)128 * 1024 * sizeof(uint4);   // 2 MB
    const size_t need16 = need8 + (size_t)64 * 2048 * sizeof(uint4);  // 4 MB

    if (ws_size >= need16) {
        uint4* Mch8 = (uint4*)d_ws;
        uint4* Mc16 = Mch8 + 128 * 1024;
        compose8_kernel<<<128, 512, 0, stream>>>(pe, po, le, ie, lo, io, Mch8);
        compose16_kernel<<<64, 512, 0, stream>>>(Mch8, Mc16);
        mesh16_kernel<<<512, 256, 0, stream>>>(Mc16, pout, (float*)d_out, out_size);
    } else {
        // ws >= 2 MB is guaranteed by every prior passing round; R16 path.
        uint4* Mch8 = (uint4*)d_ws;
        compose8_kernel<<<128, 512, 0, stream>>>(pe, po, le, ie, lo, io, Mch8);
        mesh8h_kernel<<<512, 256, 0, stream>>>(Mch8, pout, (float*)d_out, out_size);
    }
}

// Round 18
// 144.624 us; speedup vs baseline: 1.0494x; 1.0494x over previous
//
#include <hip/hip_runtime.h>
#include <hip/hip_fp16.h>

#define TWO_PI_F 6.283185307179586f

__device__ __forceinline__ float clamp02pi(float x) {
    return fminf(fmaxf(x, 0.0f), TWO_PI_F);
}

__device__ __forceinline__ float2 cmul(const float2 a, const float2 b) {
    return make_float2(a.x * b.x - a.y * b.y, a.x * b.y + a.y * b.x);
}
__device__ __forceinline__ float2 cadd(const float2 a, const float2 b) {
    return make_float2(a.x + b.x, a.y + b.y);
}
__device__ __forceinline__ float2 cscale(const float s, const float2 a) {
    return make_float2(s * a.x, s * a.y);
}
__device__ __forceinline__ float2 imul(const float r, const float2 e) {  // i*r*e
    return make_float2(-r * e.y, r * e.x);
}
__device__ __forceinline__ float2 cfma(const float2 acc, const float2 a, const float2 b) {
    return make_float2(acc.x + a.x * b.x - a.y * b.y,
                       acc.y + a.x * b.y + a.y * b.x);
}

// half2 <-> float2 via bit_cast (register-only).
__device__ __forceinline__ float2 h2f(const unsigned u) {
    return __half22float2(__builtin_bit_cast(__half2, u));
}
__device__ __forceinline__ unsigned f2h(const float2 f) {
    return __builtin_bit_cast(unsigned, __float22half2_rn(f));
}

// Band-4 composition of row r for one 4-layer step, WINDOWED pair coefs
// (math verbatim R12-R17 — verified, absmax 7.45e-9 on the fp16 path).
// sE/sO hold pairs [P0, P0+72) for the step's two sub-layers.
__device__ __forceinline__ void compose_row_w(
    const float4 (*sE)[72], const float4 (*sO)[72], const int r, const int P0,
    float4& h0, float4& h1)
{
    float2 f0, f1, f2, f3;
    if (r == 0) {
        const float4 q1 = sE[1][0], q0 = sE[0][0];   // P0 == 0 for quarter 0
        const float2 e1 = make_float2(q1.x, q1.y);
        const float2 e0 = make_float2(q0.x, q0.y);
        const float2 v2 = cscale(q1.z, e1);
        const float2 v3 = make_float2(0.0f, q1.w);
        f2 = cadd(cmul(v2, cscale(q0.z, e0)), cmul(v3, imul(q0.w, e0)));
        f3 = cadd(cmul(v2, make_float2(0.0f, q0.w)), cscale(q0.z, v3));
        f0 = make_float2(0.0f, 0.0f);
        f1 = make_float2(0.0f, 0.0f);
    } else {
        const int pidx = ((r - 1) >> 1) - P0;
        const int qidx = min(((r - 1) >> 1) + 1, 255) - P0;
        const float4 qO1 = sO[1][pidx], qO0 = sO[0][pidx];
        const float2 eO1 = make_float2(qO1.x, qO1.y);
        const float2 eO0 = make_float2(qO0.x, qO0.y);
        float2 w1, w2;
        if (r & 1) { w1 = cscale(qO1.z, eO1); w2 = make_float2(0.0f, qO1.w); }
        else       { w1 = imul(qO1.w, eO1);   w2 = make_float2(qO1.z, 0.0f); }
        const float2 u1 = cadd(cmul(w1, cscale(qO0.z, eO0)),
                               cmul(w2, imul(qO0.w, eO0)));
        const float2 u2 = cadd(cmul(w1, make_float2(0.0f, qO0.w)),
                               cscale(qO0.z, w2));
        const float4 qE1p = sE[1][pidx], qE1q = sE[1][qidx];
        const float4 qE0p = sE[0][pidx], qE0q = sE[0][qidx];
        const float2 eE1p = make_float2(qE1p.x, qE1p.y);
        const float2 eE1q = make_float2(qE1q.x, qE1q.y);
        const float2 eE0p = make_float2(qE0p.x, qE0p.y);
        const float2 eE0q = make_float2(qE0q.x, qE0q.y);
        const float2 v0 = cmul(u1, imul(qE1p.w, eE1p));
        const float2 v1 = cscale(qE1p.z, u1);
        const float2 v2 = cmul(u2, cscale(qE1q.z, eE1q));
        const float2 v3 = cmul(u2, make_float2(0.0f, qE1q.w));
        f0 = cadd(cmul(v0, cscale(qE0p.z, eE0p)), cmul(v1, imul(qE0p.w, eE0p)));
        f1 = cadd(cmul(v0, make_float2(0.0f, qE0p.w)), cscale(qE0p.z, v1));
        f2 = cadd(cmul(v2, cscale(qE0q.z, eE0q)), cmul(v3, imul(qE0q.w, eE0q)));
        f3 = cadd(cmul(v2, make_float2(0.0f, qE0q.w)), cscale(qE0q.z, v3));
    }
    h0 = make_float4(f0.x, f0.y, f1.x, f1.y);
    h1 = make_float4(f2.x, f2.y, f3.x, f3.y);
}

// ---------------------------------------------------------------------------
// Kernel 1: quarter-superstep composition (4.5x more parallel than R16's
// 128x512 version — the measured ~60 us serial tail). Grid 512 x 256:
// block q -> superstep j = q>>2 (layers 4j..4j+3), quarter = q&3, output
// rows [R0, R0+128), R0 = 128*quarter.
// Phase A: stage pair-coef window [P0, P0+72) x 4 sub-layers (trig overlap
//          vs neighbors ~3%). Phase B: band-4 for B4 rows [R0-2, R0+131]
//          (invalid rows skipped; provably never read thanks to the
//          clamp(k,0,511) in phase C). Phase C (threads 0..127): fp16
//          band-8 row R0+t -> Mch8 (layout verbatim R16).
// ---------------------------------------------------------------------------
__global__ __launch_bounds__(256) void compose8q_kernel(
    const float* __restrict__ pe, const float* __restrict__ po,
    const float* __restrict__ le, const float* __restrict__ ie,
    const float* __restrict__ lo, const float* __restrict__ io,
    uint4* __restrict__ Mch8)
{
    const int q = blockIdx.x;
    const int j = q >> 2;
    const int quarter = q & 3;
    const int R0 = 128 * quarter;
    const int P0 = (quarter == 0) ? 0 : ((R0 - 3) >> 1);
    const int t = threadIdx.x;

    __shared__ float4 sE[4][72];        // 4.5 KB
    __shared__ float4 sO[4][72];        // 4.5 KB
    __shared__ float4 B4[2][134][2];    // 8.6 KB

    // ---- Phase A: stage pair-coef window ----
    for (int it = t; it < 576; it += 256) {
        const int half = it / 288;          // 0 = E, 1 = O
        const int rem  = it % 288;
        const int sub  = rem / 72;          // sub-layer 0..3 (layer 4j+sub)
        const int w    = rem % 72;
        const int p    = P0 + w;
        if (p > 255) continue;              // never referenced
        if (half == 0) {
            const int idx = (4 * j + sub) * 256 + p;
            float s, c;
            __sincosf(clamp02pi(pe[idx]), &s, &c);
            const float a = sqrtf(1.0f - le[idx]);
            sE[sub][w] = make_float4(c, s, a * sqrtf(0.5f + ie[idx]),
                                           a * sqrtf(0.5f - ie[idx]));
        } else {
            float4 qv = make_float4(1.0f, 0.0f, 1.0f, 0.0f);
            if (p < 255) {
                const int odx = (4 * j + sub) * 255 + p;
                float s, c;
                __sincosf(clamp02pi(po[odx]), &s, &c);
                const float a = sqrtf(1.0f - lo[odx]);
                qv = make_float4(c, s, a * sqrtf(0.5f + io[odx]),
                                       a * sqrtf(0.5f - io[odx]));
            }
            sO[sub][w] = qv;
        }
    }
    __syncthreads();

    // ---- Phase B: band-4 for both child steps over the halo'd row range ----
    for (int it = t; it < 268; it += 256) {
        const int s = it / 134, slot = it % 134;
        const int row = R0 - 2 + slot;
        if (row >= 0 && row <= 511) {
            float4 h0, h1;
            compose_row_w(&sE[2 * s], &sO[2 * s], row, P0, h0, h1);
            B4[s][slot][0] = h0;
            B4[s][slot][1] = h1;
        }
    }
    __syncthreads();

    // ---- Phase C: band-8 product (verbatim R16 math), rows R0..R0+127 ----
    if (t < 128) {
        const int r = R0 + t;
        const int base = (r & 1) ? (r - 1) : (r - 2);
        const int sr = t + 2;                       // slot of row r
        const float4 wv0 = B4[1][sr][0], wv1 = B4[1][sr][1];
        const float2 w0 = make_float2(wv0.x, wv0.y), w1 = make_float2(wv0.z, wv0.w);
        const float2 w2 = make_float2(wv1.x, wv1.y), w3 = make_float2(wv1.z, wv1.w);
        float2 p0 = make_float2(0.f,0.f), p1 = p0, p2 = p0, p3 = p0,
               p4 = p0, p5 = p0, p6 = p0, p7 = p0;
        {   const int k = min(max(base, 0), 511) - (R0 - 2);
            const float4 a = B4[0][k][0], b = B4[0][k][1];
            p0 = cfma(p0, w0, make_float2(a.x, a.y));
            p1 = cfma(p1, w0, make_float2(a.z, a.w));
            p2 = cfma(p2, w0, make_float2(b.x, b.y));
            p3 = cfma(p3, w0, make_float2(b.z, b.w)); }
        {   const int k = min(max(base + 1, 0), 511) - (R0 - 2);
            const float4 a = B4[0][k][0], b = B4[0][k][1];
            p2 = cfma(p2, w1, make_float2(a.x, a.y));
            p3 = cfma(p3, w1, make_float2(a.z, a.w));
            p4 = cfma(p4, w1, make_float2(b.x, b.y));
            p5 = cfma(p5, w1, make_float2(b.z, b.w)); }
        {   const int k = min(max(base + 2, 0), 511) - (R0 - 2);
            const float4 a = B4[0][k][0], b = B4[0][k][1];
            p2 = cfma(p2, w2, make_float2(a.x, a.y));
            p3 = cfma(p3, w2, make_float2(a.z, a.w));
            p4 = cfma(p4, w2, make_float2(b.x, b.y));
            p5 = cfma(p5, w2, make_float2(b.z, b.w)); }
        {   const int k = min(max(base + 3, 0), 511) - (R0 - 2);
            const float4 a = B4[0][k][0], b = B4[0][k][1];
            p4 = cfma(p4, w3, make_float2(a.x, a.y));
            p5 = cfma(p5, w3, make_float2(a.z, a.w));
            p6 = cfma(p6, w3, make_float2(b.x, b.y));
            p7 = cfma(p7, w3, make_float2(b.z, b.w)); }
        uint4* dst = Mch8 + (size_t)j * 1024 + (r & 1) * 512 + (r >> 1);
        dst[0]   = make_uint4(f2h(p0), f2h(p1), f2h(p2), f2h(p3));
        dst[256] = make_uint4(f2h(p4), f2h(p5), f2h(p6), f2h(p7));
    }
}

// fp16 band partial apply: q packs 4 complex coefs over inputs (a,b,d,e).
__device__ __forceinline__ float2 hrow4(const uint4 q, const float2 a,
                                        const float2 b, const float2 d,
                                        const float2 e, float2 acc)
{
    acc = cfma(acc, h2f(q.x), a);
    acc = cfma(acc, h2f(q.y), b);
    acc = cfma(acc, h2f(q.z), d);
    acc = cfma(acc, h2f(q.w), e);
    return acc;
}

// ---------------------------------------------------------------------------
// Kernel 2 (verbatim R16 — verified best: 81 us, VALUBusy 59%, conflicts 0):
// band-8 pair-thread scan, fp16 coefs, grid 512 x 256, 2 blocks/CU, ONE
// barrier per 8-layer superstep, padded double-buffered fp32 LDS state.
// ---------------------------------------------------------------------------
__global__ __launch_bounds__(256) void mesh8h_kernel(
    const uint4* __restrict__ Mch,
    const float* __restrict__ pout,
    float* __restrict__ out, const int out_size)
{
    const int t   = threadIdx.x;   // row-pair 0..255
    const int col = blockIdx.x;    // column 0..511

    __shared__ float4 S[2][260];   // [buf][pair+2] = {T.x,T.y,B.x,B.y}

    float2 T = make_float2((2 * t     == col) ? 1.0f : 0.0f, 0.0f);
    float2 B = make_float2((2 * t + 1 == col) ? 1.0f : 0.0f, 0.0f);
    S[0][t + 2] = make_float4(T.x, T.y, B.x, B.y);
    if (t < 2) {
        const float4 z = make_float4(0.f, 0.f, 0.f, 0.f);
        S[0][t] = z; S[1][t] = z;
        S[0][258 + t] = z; S[1][258 + t] = z;
    }

    uint4 c0 = Mch[t],       c1 = Mch[256 + t],
          c2 = Mch[512 + t], c3 = Mch[768 + t];
    __syncthreads();

#pragma unroll 1
    for (int i = 0; i < 128; ++i) {
        const int nb = ((i + 1) & 127) * 1024 + t;      // prefetch (wrap ok)
        const uint4 n0 = Mch[nb],       n1 = Mch[nb + 256],
                    n2 = Mch[nb + 512], n3 = Mch[nb + 768];

        const float4* SS = S[i & 1];
        const float4 s0 = SS[t], s1 = SS[t + 1], s3 = SS[t + 3], s4 = SS[t + 4];

        float2 YT = hrow4(c0, make_float2(s0.x, s0.y), make_float2(s0.z, s0.w),
                              make_float2(s1.x, s1.y), make_float2(s1.z, s1.w),
                          make_float2(0.f, 0.f));
        YT = hrow4(c1, T, B,
                       make_float2(s3.x, s3.y), make_float2(s3.z, s3.w), YT);
        float2 YB = hrow4(c2, make_float2(s1.x, s1.y), make_float2(s1.z, s1.w),
                              T, B, make_float2(0.f, 0.f));
        YB = hrow4(c3, make_float2(s3.x, s3.y), make_float2(s3.z, s3.w),
                       make_float2(s4.x, s4.y), make_float2(s4.z, s4.w), YB);
        T = YT; B = YB;
        S[(i + 1) & 1][t + 2] = make_float4(T.x, T.y, B.x, B.y);
        __syncthreads();

        c0 = n0; c1 = n1; c2 = n2; c3 = n3;
    }

    // ---- output phases; expected output = Re(M), row-major, guarded ----
    float s0p, c0p, s1p, c1p;
    __sincosf(clamp02pi(pout[2 * t]),     &s0p, &c0p);
    __sincosf(clamp02pi(pout[2 * t + 1]), &s1p, &c1p);
    const int i0 = (2 * t) * 512 + col;
    const int i1 = i0 + 512;
    if (i0 < out_size) out[i0] = c0p * T.x - s0p * T.y;
    if (i1 < out_size) out[i1] = c1p * B.x - s1p * B.y;
}

// ---------------------------------------------------------------------------
// Fallback (verbatim R5 kernel, known-passing) — used only if ws too small.
// ---------------------------------------------------------------------------
__global__ __launch_bounds__(256) void mesh_kernel(
    const float* __restrict__ pe, const float* __restrict__ po,
    const float* __restrict__ pout,
    const float* __restrict__ le, const float* __restrict__ ie,
    const float* __restrict__ lo, const float* __restrict__ io,
    float* __restrict__ out, const int out_size)
{
    const int p = threadIdx.x;
    const int b = blockIdx.x;

    __shared__ float4 P[2][256];

    P[0][p] = (p == b) ? make_float4(1.0f, 0.0f, 0.0f, 0.0f)
                       : make_float4(0.0f, 0.0f, 0.0f, 0.0f);
    P[1][p] = (p == b) ? make_float4(0.0f, 0.0f, 1.0f, 0.0f)
                       : make_float4(0.0f, 0.0f, 0.0f, 0.0f);

#pragma unroll 1
    for (int i = 0; i < 256; ++i) {
        const int e0 = (2 * i) * 256 + p, e1 = e0 + 256;
        const float pe0 = pe[e0], le0 = le[e0], ie0 = ie[e0];
        const float pe1 = pe[e1], le1 = le[e1], ie1 = ie[e1];
        float po0 = 0.0f, lo0 = 0.0f, io0 = 0.0f;
        float po1 = 0.0f, lo1 = 0.0f, io1 = 0.0f;
        if (p < 255) {
            const int o0 = (2 * i) * 255 + p, o1 = o0 + 255;
            po0 = po[o0]; lo0 = lo[o0]; io0 = io[o0];
            po1 = po[o1]; lo1 = lo[o1]; io1 = io[o1];
        }

        float4 v0 = P[0][p];
        float4 v1 = P[1][p];
#pragma unroll
        for (int j = 0; j < 2; ++j) {
            float s, c;
            __sincosf(clamp02pi(j ? pe1 : pe0), &s, &c);
            const float a  = sqrtf(1.0f - (j ? le1 : le0));
            const float tt = a * sqrtf(0.5f + (j ? ie1 : ie0));
            const float rr = a * sqrtf(0.5f - (j ? ie1 : ie0));
            {
                const float ptr_ = c * v0.x - s * v0.y;
                const float pti_ = c * v0.y + s * v0.x;
                v0 = make_float4(tt * ptr_ - rr * v0.w, tt * pti_ + rr * v0.z,
                                 tt * v0.z - rr * pti_, tt * v0.w + rr * ptr_);
            }
            {
                const float ptr_ = c * v1.x - s * v1.y;
                const float pti_ = c * v1.y + s * v1.x;
                v1 = make_float4(tt * ptr_ - rr * v1.w, tt * pti_ + rr * v1.z,
                                 tt * v1.z - rr * pti_, tt * v1.w + rr * ptr_);
            }
        }
        P[0][p] = v0;
        P[1][p] = v1;
        __syncthreads();

        if (p < 255) {
            float2 top0 = make_float2(P[0][p].z, P[0][p].w);
            float2 bot0 = make_float2(P[0][p + 1].x, P[0][p + 1].y);
            float2 top1 = make_float2(P[1][p].z, P[1][p].w);
            float2 bot1 = make_float2(P[1][p + 1].x, P[1][p + 1].y);
#pragma unroll
            for (int j = 0; j < 2; ++j) {
                float s, c;
                __sincosf(clamp02pi(j ? po1 : po0), &s, &c);
                const float a  = sqrtf(1.0f - (j ? lo1 : lo0));
                const float tt = a * sqrtf(0.5f + (j ? io1 : io0));
                const float rr = a * sqrtf(0.5f - (j ? io1 : io0));
                {
                    const float ptr_ = c * top0.x - s * top0.y;
                    const float pti_ = c * top0.y + s * top0.x;
                    const float nbx = tt * bot0.x - rr * pti_;
                    const float nby = tt * bot0.y + rr * ptr_;
                    top0 = make_float2(tt * ptr_ - rr * bot0.y, tt * pti_ + rr * bot0.x);
                    bot0 = make_float2(nbx, nby);
                }
                {
                    const float ptr_ = c * top1.x - s * top1.y;
                    const float pti_ = c * top1.y + s * top1.x;
                    const float nbx = tt * bot1.x - rr * pti_;
                    const float nby = tt * bot1.y + rr * ptr_;
                    top1 = make_float2(tt * ptr_ - rr * bot1.y, tt * pti_ + rr * bot1.x);
                    bot1 = make_float2(nbx, nby);
                }
            }
            P[0][p].z = top0.x; P[0][p].w = top0.y;
            P[0][p + 1].x = bot0.x; P[0][p + 1].y = bot0.y;
            P[1][p].z = top1.x; P[1][p].w = top1.y;
            P[1][p + 1].x = bot1.x; P[1][p + 1].y = bot1.y;
        }
        __syncthreads();
    }

    const float4 v0 = P[0][p];
    const float4 v1 = P[1][p];
    float s0, c0, s1, c1;
    __sincosf(clamp02pi(pout[2 * p]),     &s0, &c0);
    __sincosf(clamp02pi(pout[2 * p + 1]), &s1, &c1);

    float4 w0, w1;
    w0.x = c0 * v0.x - s0 * v0.y;  w0.y = c0 * v0.y + s0 * v0.x;
    w0.z = c0 * v1.x - s0 * v1.y;  w0.w = c0 * v1.y + s0 * v1.x;
    w1.x = c1 * v0.z - s1 * v0.w;  w1.y = c1 * v0.w + s1 * v0.z;
    w1.z = c1 * v1.z - s1 * v1.w;  w1.w = c1 * v1.w + s1 * v1.z;

    const int i0 = (2 * p) * 512 + 2 * b;
    const int i1 = (2 * p + 1) * 512 + 2 * b;
    if (i0 + 1 < out_size) *(float2*)(out + i0) = make_float2(w0.x, w0.z);
    if (i1 + 1 < out_size) *(float2*)(out + i1) = make_float2(w1.x, w1.z);
}

extern "C" void kernel_launch(void* const* d_in, const int* in_sizes, int n_in,
                              void* d_out, int out_size, void* d_ws, size_t ws_size,
                              hipStream_t stream)
{
    const float* pe   = (const float*)d_in[0];  // pc_even_phases  [512][256]
    const float* po   = (const float*)d_in[1];  // pc_odd_phases   [512][255]
    const float* pout = (const float*)d_in[2];  // pc_out_phases   [512]
    const float* le   = (const float*)d_in[3];  // mmi_loss_even   [512][256]
    const float* ie   = (const float*)d_in[4];  // mmi_imb_even    [512][256]
    const float* lo   = (const float*)d_in[5];  // mmi_loss_odd    [512][255]
    const float* io   = (const float*)d_in[6];  // mmi_imb_odd     [512][255]

    const size_t need = (size_t)128 * 1024 * sizeof(uint4);  // 2 MB
    if (ws_size >= need) {
        uint4* Mch8 = (uint4*)d_ws;
        compose8q_kernel<<<512, 256, 0, stream>>>(pe, po, le, ie, lo, io, Mch8);
        mesh8h_kernel<<<512, 256, 0, stream>>>(Mch8, pout, (float*)d_out, out_size);
    } else {
        mesh_kernel<<<256, 256, 0, stream>>>(pe, po, pout, le, ie, lo, io,
                                             (float*)d_out, out_size);
    }
}

// Round 19
// 140.863 us; speedup vs baseline: 1.0774x; 1.0267x over previous
//
#include <hip/hip_runtime.h>
#include <hip/hip_fp16.h>

#define TWO_PI_F 6.283185307179586f

__device__ __forceinline__ float clamp02pi(float x) {
    return fminf(fmaxf(x, 0.0f), TWO_PI_F);
}

__device__ __forceinline__ float2 cmul(const float2 a, const float2 b) {
    return make_float2(a.x * b.x - a.y * b.y, a.x * b.y + a.y * b.x);
}
__device__ __forceinline__ float2 cadd(const float2 a, const float2 b) {
    return make_float2(a.x + b.x, a.y + b.y);
}
__device__ __forceinline__ float2 cscale(const float s, const float2 a) {
    return make_float2(s * a.x, s * a.y);
}
__device__ __forceinline__ float2 imul(const float r, const float2 e) {  // i*r*e
    return make_float2(-r * e.y, r * e.x);
}
__device__ __forceinline__ float2 cfma(const float2 acc, const float2 a, const float2 b) {
    return make_float2(acc.x + a.x * b.x - a.y * b.y,
                       acc.y + a.x * b.y + a.y * b.x);
}

// half2 <-> float2 via bit_cast (register-only).
__device__ __forceinline__ float2 h2f(const unsigned u) {
    return __half22float2(__builtin_bit_cast(__half2, u));
}
__device__ __forceinline__ unsigned f2h(const float2 f) {
    return __builtin_bit_cast(unsigned, __float22half2_rn(f));
}

// Band-4 composition of row r for one 4-layer step, WINDOWED pair coefs
// (math verbatim R12-R18 — verified, absmax 7.45e-9 on the fp16 path).
__device__ __forceinline__ void compose_row_w(
    const float4 (*sE)[72], const float4 (*sO)[72], const int r, const int P0,
    float4& h0, float4& h1)
{
    float2 f0, f1, f2, f3;
    if (r == 0) {
        const float4 q1 = sE[1][0], q0 = sE[0][0];   // P0 == 0 for quarter 0
        const float2 e1 = make_float2(q1.x, q1.y);
        const float2 e0 = make_float2(q0.x, q0.y);
        const float2 v2 = cscale(q1.z, e1);
        const float2 v3 = make_float2(0.0f, q1.w);
        f2 = cadd(cmul(v2, cscale(q0.z, e0)), cmul(v3, imul(q0.w, e0)));
        f3 = cadd(cmul(v2, make_float2(0.0f, q0.w)), cscale(q0.z, v3));
        f0 = make_float2(0.0f, 0.0f);
        f1 = make_float2(0.0f, 0.0f);
    } else {
        const int pidx = ((r - 1) >> 1) - P0;
        const int qidx = min(((r - 1) >> 1) + 1, 255) - P0;
        const float4 qO1 = sO[1][pidx], qO0 = sO[0][pidx];
        const float2 eO1 = make_float2(qO1.x, qO1.y);
        const float2 eO0 = make_float2(qO0.x, qO0.y);
        float2 w1, w2;
        if (r & 1) { w1 = cscale(qO1.z, eO1); w2 = make_float2(0.0f, qO1.w); }
        else       { w1 = imul(qO1.w, eO1);   w2 = make_float2(qO1.z, 0.0f); }
        const float2 u1 = cadd(cmul(w1, cscale(qO0.z, eO0)),
                               cmul(w2, imul(qO0.w, eO0)));
        const float2 u2 = cadd(cmul(w1, make_float2(0.0f, qO0.w)),
                               cscale(qO0.z, w2));
        const float4 qE1p = sE[1][pidx], qE1q = sE[1][qidx];
        const float4 qE0p = sE[0][pidx], qE0q = sE[0][qidx];
        const float2 eE1p = make_float2(qE1p.x, qE1p.y);
        const float2 eE1q = make_float2(qE1q.x, qE1q.y);
        const float2 eE0p = make_float2(qE0p.x, qE0p.y);
        const float2 eE0q = make_float2(qE0q.x, qE0q.y);
        const float2 v0 = cmul(u1, imul(qE1p.w, eE1p));
        const float2 v1 = cscale(qE1p.z, u1);
        const float2 v2 = cmul(u2, cscale(qE1q.z, eE1q));
        const float2 v3 = cmul(u2, make_float2(0.0f, qE1q.w));
        f0 = cadd(cmul(v0, cscale(qE0p.z, eE0p)), cmul(v1, imul(qE0p.w, eE0p)));
        f1 = cadd(cmul(v0, make_float2(0.0f, qE0p.w)), cscale(qE0p.z, v1));
        f2 = cadd(cmul(v2, cscale(qE0q.z, eE0q)), cmul(v3, imul(qE0q.w, eE0q)));
        f3 = cadd(cmul(v2, make_float2(0.0f, qE0q.w)), cscale(qE0q.z, v3));
    }
    h0 = make_float4(f0.x, f0.y, f1.x, f1.y);
    h1 = make_float4(f2.x, f2.y, f3.x, f3.y);
}

// ---------------------------------------------------------------------------
// Kernel 1: quarter-superstep composition (verbatim R18 — verified; only the
// OUTPUT LAYOUT changed to row-direct for the row-per-thread mesh):
//   Mch8[j*1024 + r]       = band cols 0..3 (4 complex, fp16)
//   Mch8[j*1024 + 512 + r] = band cols 4..7
// Row 2t window base 2t-4; row 2t+1 base 2t-2; out-of-window entries EXACT 0.
// ---------------------------------------------------------------------------
__global__ __launch_bounds__(256) void compose8q_kernel(
    const float* __restrict__ pe, const float* __restrict__ po,
    const float* __restrict__ le, const float* __restrict__ ie,
    const float* __restrict__ lo, const float* __restrict__ io,
    uint4* __restrict__ Mch8)
{
    const int q = blockIdx.x;
    const int j = q >> 2;
    const int quarter = q & 3;
    const int R0 = 128 * quarter;
    const int P0 = (quarter == 0) ? 0 : ((R0 - 3) >> 1);
    const int t = threadIdx.x;

    __shared__ float4 sE[4][72];
    __shared__ float4 sO[4][72];
    __shared__ float4 B4[2][134][2];

    // ---- Phase A: stage pair-coef window [P0, P0+72) ----
    for (int it = t; it < 576; it += 256) {
        const int half = it / 288;
        const int rem  = it % 288;
        const int sub  = rem / 72;
        const int w    = rem % 72;
        const int p    = P0 + w;
        if (p > 255) continue;
        if (half == 0) {
            const int idx = (4 * j + sub) * 256 + p;
            float s, c;
            __sincosf(clamp02pi(pe[idx]), &s, &c);
            const float a = sqrtf(1.0f - le[idx]);
            sE[sub][w] = make_float4(c, s, a * sqrtf(0.5f + ie[idx]),
                                           a * sqrtf(0.5f - ie[idx]));
        } else {
            float4 qv = make_float4(1.0f, 0.0f, 1.0f, 0.0f);
            if (p < 255) {
                const int odx = (4 * j + sub) * 255 + p;
                float s, c;
                __sincosf(clamp02pi(po[odx]), &s, &c);
                const float a = sqrtf(1.0f - lo[odx]);
                qv = make_float4(c, s, a * sqrtf(0.5f + io[odx]),
                                       a * sqrtf(0.5f - io[odx]));
            }
            sO[sub][w] = qv;
        }
    }
    __syncthreads();

    // ---- Phase B: band-4 for both child steps over rows [R0-2, R0+131] ----
    for (int it = t; it < 268; it += 256) {
        const int s = it / 134, slot = it % 134;
        const int row = R0 - 2 + slot;
        if (row >= 0 && row <= 511) {
            float4 h0, h1;
            compose_row_w(&sE[2 * s], &sO[2 * s], row, P0, h0, h1);
            B4[s][slot][0] = h0;
            B4[s][slot][1] = h1;
        }
    }
    __syncthreads();

    // ---- Phase C: band-8 product (verbatim R16 math), rows R0..R0+127 ----
    if (t < 128) {
        const int r = R0 + t;
        const int base = (r & 1) ? (r - 1) : (r - 2);
        const int sr = t + 2;
        const float4 wv0 = B4[1][sr][0], wv1 = B4[1][sr][1];
        const float2 w0 = make_float2(wv0.x, wv0.y), w1 = make_float2(wv0.z, wv0.w);
        const float2 w2 = make_float2(wv1.x, wv1.y), w3 = make_float2(wv1.z, wv1.w);
        float2 p0 = make_float2(0.f,0.f), p1 = p0, p2 = p0, p3 = p0,
               p4 = p0, p5 = p0, p6 = p0, p7 = p0;
        {   const int k = min(max(base, 0), 511) - (R0 - 2);
            const float4 a = B4[0][k][0], b = B4[0][k][1];
            p0 = cfma(p0, w0, make_float2(a.x, a.y));
            p1 = cfma(p1, w0, make_float2(a.z, a.w));
            p2 = cfma(p2, w0, make_float2(b.x, b.y));
            p3 = cfma(p3, w0, make_float2(b.z, b.w)); }
        {   const int k = min(max(base + 1, 0), 511) - (R0 - 2);
            const float4 a = B4[0][k][0], b = B4[0][k][1];
            p2 = cfma(p2, w1, make_float2(a.x, a.y));
            p3 = cfma(p3, w1, make_float2(a.z, a.w));
            p4 = cfma(p4, w1, make_float2(b.x, b.y));
            p5 = cfma(p5, w1, make_float2(b.z, b.w)); }
        {   const int k = min(max(base + 2, 0), 511) - (R0 - 2);
            const float4 a = B4[0][k][0], b = B4[0][k][1];
            p2 = cfma(p2, w2, make_float2(a.x, a.y));
            p3 = cfma(p3, w2, make_float2(a.z, a.w));
            p4 = cfma(p4, w2, make_float2(b.x, b.y));
            p5 = cfma(p5, w2, make_float2(b.z, b.w)); }
        {   const int k = min(max(base + 3, 0), 511) - (R0 - 2);
            const float4 a = B4[0][k][0], b = B4[0][k][1];
            p4 = cfma(p4, w3, make_float2(a.x, a.y));
            p5 = cfma(p5, w3, make_float2(a.z, a.w));
            p6 = cfma(p6, w3, make_float2(b.x, b.y));
            p7 = cfma(p7, w3, make_float2(b.z, b.w)); }
        uint4* dst = Mch8 + (size_t)j * 1024 + r;     // row-direct layout
        dst[0]   = make_uint4(f2h(p0), f2h(p1), f2h(p2), f2h(p3));
        dst[512] = make_uint4(f2h(p4), f2h(p5), f2h(p6), f2h(p7));
    }
}

// fp16 band partial apply: q packs 4 complex coefs over inputs (a,b,d,e).
__device__ __forceinline__ float2 hrow4(const uint4 q, const float2 a,
                                        const float2 b, const float2 d,
                                        const float2 e, float2 acc)
{
    acc = cfma(acc, h2f(q.x), a);
    acc = cfma(acc, h2f(q.y), b);
    acc = cfma(acc, h2f(q.z), d);
    acc = cfma(acc, h2f(q.w), e);
    return acc;
}

// ---------------------------------------------------------------------------
// Kernel 2: ROW-per-thread band-8 scan. Grid 512 x 512 = 262144 threads =
// 16 waves/CU (2x mesh8h's 8 — the measured limiter was issue/latency at low
// occupancy). Thread r owns row r of column `col`; per-row arithmetic is
// bitwise-identical to mesh8h (same coefs, same ascending-window order).
// State: padded double-buffered LDS float4 per PAIR (slots +2; pads 0,1 and
// 258,259 zero — they feed exactly-zero band coefs, verified R16-R18).
// Window slots: even r=2t -> t..t+3; odd r=2t+1 -> t+1..t+4 (4 x b128 reads,
// 16 B lane stride = conflict-free per R15-R18 measurement). One float2
// write + ONE barrier per 8-layer superstep (128 total).
// ---------------------------------------------------------------------------
__global__ __launch_bounds__(512) void mesh8r_kernel(
    const uint4* __restrict__ Mch,
    const float* __restrict__ pout,
    float* __restrict__ out, const int out_size)
{
    const int r   = threadIdx.x;   // row 0..511
    const int col = blockIdx.x;    // column 0..511
    const int t   = r >> 1;
    const int odd = r & 1;

    __shared__ float4 S[2][264];   // [buf][pair+2] = {T.x,T.y,B.x,B.y}

    float2 Y = make_float2((r == col) ? 1.0f : 0.0f, 0.0f);
    ((float2*)&S[0][t + 2])[odd] = Y;
    if (r < 2) {
        const float4 z = make_float4(0.f, 0.f, 0.f, 0.f);
        S[0][r] = z; S[1][r] = z;
        S[0][258 + r] = z; S[1][258 + r] = z;
    }

    uint4 c0 = Mch[r], c1 = Mch[512 + r];
    __syncthreads();

#pragma unroll 1
    for (int i = 0; i < 128; ++i) {
        const int nb = ((i + 1) & 127) * 1024 + r;      // prefetch (wrap ok)
        const uint4 n0 = Mch[nb], n1 = Mch[nb + 512];

        const float4* SS = S[i & 1];
        const int b0 = t + odd;                         // first window slot
        const float4 q0 = SS[b0],     q1 = SS[b0 + 1],
                     q2 = SS[b0 + 2], q3 = SS[b0 + 3];

        Y = hrow4(c0, make_float2(q0.x, q0.y), make_float2(q0.z, q0.w),
                      make_float2(q1.x, q1.y), make_float2(q1.z, q1.w),
                  make_float2(0.f, 0.f));
        Y = hrow4(c1, make_float2(q2.x, q2.y), make_float2(q2.z, q2.w),
                      make_float2(q3.x, q3.y), make_float2(q3.z, q3.w), Y);

        ((float2*)&S[(i + 1) & 1][t + 2])[odd] = Y;
        __syncthreads();

        c0 = n0; c1 = n1;
    }

    // ---- output phase; expected output = Re(M), row-major, guarded ----
    float s, c;
    __sincosf(clamp02pi(pout[r]), &s, &c);
    const int o = r * 512 + col;
    if (o < out_size) out[o] = c * Y.x - s * Y.y;
}

// ---------------------------------------------------------------------------
// Fallback (verbatim R5 kernel, known-passing) — used only if ws too small.
// ---------------------------------------------------------------------------
__global__ __launch_bounds__(256) void mesh_kernel(
    const float* __restrict__ pe, const float* __restrict__ po,
    const float* __restrict__ pout,
    const float* __restrict__ le, const float* __restrict__ ie,
    const float* __restrict__ lo, const float* __restrict__ io,
    float* __restrict__ out, const int out_size)
{
    const int p = threadIdx.x;
    const int b = blockIdx.x;

    __shared__ float4 P[2][256];

    P[0][p] = (p == b) ? make_float4(1.0f, 0.0f, 0.0f, 0.0f)
                       : make_float4(0.0f, 0.0f, 0.0f, 0.0f);
    P[1][p] = (p == b) ? make_float4(0.0f, 0.0f, 1.0f, 0.0f)
                       : make_float4(0.0f, 0.0f, 0.0f, 0.0f);

#pragma unroll 1
    for (int i = 0; i < 256; ++i) {
        const int e0 = (2 * i) * 256 + p, e1 = e0 + 256;
        const float pe0 = pe[e0], le0 = le[e0], ie0 = ie[e0];
        const float pe1 = pe[e1], le1 = le[e1], ie1 = ie[e1];
        float po0 = 0.0f, lo0 = 0.0f, io0 = 0.0f;
        float po1 = 0.0f, lo1 = 0.0f, io1 = 0.0f;
        if (p < 255) {
            const int o0 = (2 * i) * 255 + p, o1 = o0 + 255;
            po0 = po[o0]; lo0 = lo[o0]; io0 = io[o0];
            po1 = po[o1]; lo1 = lo[o1]; io1 = io[o1];
        }

        float4 v0 = P[0][p];
        float4 v1 = P[1][p];
#pragma unroll
        for (int j = 0; j < 2; ++j) {
            float s, c;
            __sincosf(clamp02pi(j ? pe1 : pe0), &s, &c);
            const float a  = sqrtf(1.0f - (j ? le1 : le0));
            const float tt = a * sqrtf(0.5f + (j ? ie1 : ie0));
            const float rr = a * sqrtf(0.5f - (j ? ie1 : ie0));
            {
                const float ptr_ = c * v0.x - s * v0.y;
                const float pti_ = c * v0.y + s * v0.x;
                v0 = make_float4(tt * ptr_ - rr * v0.w, tt * pti_ + rr * v0.z,
                                 tt * v0.z - rr * pti_, tt * v0.w + rr * ptr_);
            }
            {
                const float ptr_ = c * v1.x - s * v1.y;
                const float pti_ = c * v1.y + s * v1.x;
                v1 = make_float4(tt * ptr_ - rr * v1.w, tt * pti_ + rr * v1.z,
                                 tt * v1.z - rr * pti_, tt * v1.w + rr * ptr_);
            }
        }
        P[0][p] = v0;
        P[1][p] = v1;
        __syncthreads();

        if (p < 255) {
            float2 top0 = make_float2(P[0][p].z, P[0][p].w);
            float2 bot0 = make_float2(P[0][p + 1].x, P[0][p + 1].y);
            float2 top1 = make_float2(P[1][p].z, P[1][p].w);
            float2 bot1 = make_float2(P[1][p + 1].x, P[1][p + 1].y);
#pragma unroll
            for (int j = 0; j < 2; ++j) {
                float s, c;
                __sincosf(clamp02pi(j ? po1 : po0), &s, &c);
                const float a  = sqrtf(1.0f - (j ? lo1 : lo0));
                const float tt = a * sqrtf(0.5f + (j ? io1 : io0));
                const float rr = a * sqrtf(0.5f - (j ? io1 : io0));
                {
                    const float ptr_ = c * top0.x - s * top0.y;
                    const float pti_ = c * top0.y + s * top0.x;
                    const float nbx = tt * bot0.x - rr * pti_;
                    const float nby = tt * bot0.y + rr * ptr_;
                    top0 = make_float2(tt * ptr_ - rr * bot0.y, tt * pti_ + rr * bot0.x);
                    bot0 = make_float2(nbx, nby);
                }
                {
                    const float ptr_ = c * top1.x - s * top1.y;
                    const float pti_ = c * top1.y + s * top1.x;
                    const float nbx = tt * bot1.x - rr * pti_;
                    const float nby = tt * bot1.y + rr * ptr_;
                    top1 = make_float2(tt * ptr_ - rr * bot1.y, tt * pti_ + rr * bot1.x);
                    bot1 = make_float2(nbx, nby);
                }
            }
            P[0][p].z = top0.x; P[0][p].w = top0.y;
            P[0][p + 1].x = bot0.x; P[0][p + 1].y = bot0.y;
            P[1][p].z = top1.x; P[1][p].w = top1.y;
            P[1][p + 1].x = bot1.x; P[1][p + 1].y = bot1.y;
        }
        __syncthreads();
    }

    const float4 v0 = P[0][p];
    const float4 v1 = P[1][p];
    float s0, c0, s1, c1;
    __sincosf(clamp02pi(pout[2 * p]),     &s0, &c0);
    __sincosf(clamp02pi(pout[2 * p + 1]), &s1, &c1);

    float4 w0, w1;
    w0.x = c0 * v0.x - s0 * v0.y;  w0.y = c0 * v0.y + s0 * v0.x;
    w0.z = c0 * v1.x - s0 * v1.y;  w0.w = c0 * v1.y + s0 * v1.x;
    w1.x = c1 * v0.z - s1 * v0.w;  w1.y = c1 * v0.w + s1 * v0.z;
    w1.z = c1 * v1.z - s1 * v1.w;  w1.w = c1 * v1.w + s1 * v1.z;

    const int i0 = (2 * p) * 512 + 2 * b;
    const int i1 = (2 * p + 1) * 512 + 2 * b;
    if (i0 + 1 < out_size) *(float2*)(out + i0) = make_float2(w0.x, w0.z);
    if (i1 + 1 < out_size) *(float2*)(out + i1) = make_float2(w1.x, w1.z);
}

extern "C" void kernel_launch(void* const* d_in, const int* in_sizes, int n_in,
                              void* d_out, int out_size, void* d_ws, size_t ws_size,
                              hipStream_t stream)
{
    const float* pe   = (const float*)d_in[0];  // pc_even_phases  [512][256]
    const float* po   = (const float*)d_in[1];  // pc_odd_phases   [512][255]
    const float* pout = (const float*)d_in[2];  // pc_out_phases   [512]
    const float* le   = (const float*)d_in[3];  // mmi_loss_even   [512][256]
    const float* ie   = (const float*)d_in[4];  // mmi_imb_even    [512][256]
    const float* lo   = (const float*)d_in[5];  // mmi_loss_odd    [512][255]
    const float* io   = (const float*)d_in[6];  // mmi_imb_odd     [512][255]

    const size_t need = (size_t)128 * 1024 * sizeof(uint4);  // 2 MB
    if (ws_size >= need) {
        uint4* Mch8 = (uint4*)d_ws;
        compose8q_kernel<<<512, 256, 0, stream>>>(pe, po, le, ie, lo, io, Mch8);
        mesh8r_kernel<<<512, 512, 0, stream>>>(Mch8, pout, (float*)d_out, out_size);
    } else {
        mesh_kernel<<<256, 256, 0, stream>>>(pe, po, pout, le, ie, lo, io,
                                             (float*)d_out, out_size);
    }
}